// Round 3
// baseline (332.711 us; speedup 1.0000x reference)
//
#include <hip/hip_runtime.h>
#include <cstdint>

// ---------------------------------------------------------------------------
// K1: 1x1 conv 256->8 on 64x64 maps. x[4,256,64,64] * w[8,256] + b[8]
// block = 256 threads = (4 c-groups x 64 pixels), one (b,row) per block.
// ---------------------------------------------------------------------------
__global__ __launch_bounds__(256) void k_conv(const float* __restrict__ x,
                                              const float* __restrict__ w,
                                              const float* __restrict__ bias,
                                              float* __restrict__ y) {
  __shared__ float wl[2048];          // conv_w [8][256]
  __shared__ float red[4][64][9];     // pad 9: conflict-free
  const int tid = threadIdx.x;
#pragma unroll
  for (int i = 0; i < 8; i++) { int idx = tid + i * 256; wl[idx] = w[idx]; }
  const int bi = blockIdx.x >> 6, row = blockIdx.x & 63;
  const int hwi = tid & 63, cg = tid >> 6;
  const float* xp = x + (((size_t)(bi * 256 + cg * 64)) * 64 + row) * 64 + hwi;
  float acc[8] = {0.f, 0.f, 0.f, 0.f, 0.f, 0.f, 0.f, 0.f};
  __syncthreads();
#pragma unroll 4
  for (int c = 0; c < 64; c++) {
    float v = xp[(size_t)c * 4096];
#pragma unroll
    for (int o = 0; o < 8; o++) acc[o] += v * wl[o * 256 + cg * 64 + c];
  }
#pragma unroll
  for (int o = 0; o < 8; o++) red[cg][hwi][o] = acc[o];
  __syncthreads();
#pragma unroll
  for (int i = 0; i < 2; i++) {
    int p = tid + i * 256; int o = p >> 6, hw = p & 63;
    float sv = red[0][hw][o] + red[1][hw][o] + red[2][hw][o] + red[3][hw][o] + bias[o];
    y[(((size_t)(bi * 8 + o)) * 64 + row) * 64 + hw] = sv;
  }
}

// ---------------------------------------------------------------------------
// K2: bilinear-upsample(64->512, align_corners) argmax over 8ch, 4x4 mean
// pool of one-hot -> fm[4,8,128,128]. One thread per pooled cell (16 pixels).
// ---------------------------------------------------------------------------
__global__ __launch_bounds__(256) void k_pool(const float* __restrict__ ys,
                                              float* __restrict__ fm) {
  const int g = blockIdx.x * 256 + threadIdx.x;
  const int bi = g >> 14, rem = g & 16383;
  const int sm = rem >> 7, tm = rem & 127;
  int cnt[8] = {0, 0, 0, 0, 0, 0, 0, 0};
  const float* yb = ys + (size_t)bi * 8 * 4096;
#pragma unroll
  for (int py = 0; py < 4; py++) {
    const int s = sm * 4 + py;
    float ph = s * (63.0f / 511.0f); int lh = (int)ph; float wh = ph - (float)lh;
    const int dh = (lh < 63) ? 64 : 0;
#pragma unroll
    for (int px = 0; px < 4; px++) {
      const int t = tm * 4 + px;
      float pw = t * (63.0f / 511.0f); int lt = (int)pw; float wt = pw - (float)lt;
      const int dt = (lt < 63) ? 1 : 0;
      const float w00 = (1.f - wh) * (1.f - wt), w01 = (1.f - wh) * wt;
      const float w10 = wh * (1.f - wt), w11 = wh * wt;
      const int base = lh * 64 + lt;
      float best = 0.f; int am = 0;
#pragma unroll
      for (int c = 0; c < 8; c++) {
        const float* yc = yb + c * 4096 + base;
        float v = w00 * yc[0] + w01 * yc[dt] + w10 * yc[dh] + w11 * yc[dh + dt];
        if (c == 0) { best = v; } else if (v > best) { best = v; am = c; }
      }
#pragma unroll
      for (int c = 0; c < 8; c++) cnt[c] += (am == c);
    }
  }
  const size_t ob = ((size_t)bi * 8) << 14;
#pragma unroll
  for (int c = 0; c < 8; c++)
    fm[ob + ((size_t)c << 14) + (sm << 7) + tm] = (float)cnt[c] * (1.0f / 16.0f);
}

// ---------------------------------------------------------------------------
// K4 (fused): per (b,c): corr_raw[4096,64] = A[4096,256] @ U^T, U = unfold(fm).
// Also: passthrough A->out2 and per-row nonzero count (free riders on staging).
// Block: 256 threads = 32 q-groups x 8 p-groups; each thread: 8q x 8p outputs.
// Per kk: 2 b128 A reads (8-lane broadcast groups) + 2 b128 U reads (broadcast)
// feed 64 FMAs -> 1.0 B/FLOP LDS traffic, VALU/LDS balanced, HBM-bound overall.
// grid = (16 q-tiles, 32 bc).
// ---------------------------------------------------------------------------
__global__ __launch_bounds__(256, 2) void k_corr(const float* __restrict__ A,
                                                 const float* __restrict__ fm,
                                                 float* __restrict__ Aout,
                                                 float* __restrict__ corr,
                                                 float* __restrict__ nzinv) {
  __shared__ __align__(16) float At[32][260];   // [kk][q] transposed, pad 260
  __shared__ __align__(16) float Uts[32][64];   // [kk][p]
  __shared__ int nzc[256];
  const int tid = threadIdx.x;
  const int bc = blockIdx.y;
  const int qb = blockIdx.x << 8;
  const float* Ab = A + ((size_t)bc * 4096 + qb) * 256;
  float* Ob = Aout + ((size_t)bc * 4096 + qb) * 256;
  const float* fmb = fm + ((size_t)bc << 14);
  nzc[tid] = 0;
  const int pg = tid & 7, qg = tid >> 3;
  const int p0 = pg << 3, q0 = qg << 3;

  int fq[8], fk[8], ul[8], up[8];
#pragma unroll
  for (int i = 0; i < 8; i++) {
    const int f = tid + (i << 8);
    fq[i] = f >> 3; fk[i] = (f & 7) << 2;   // A loader: q-row, k-offset
    ul[i] = f >> 6; up[i] = f & 63;         // U loader: kk, p
  }

  float4 ar[8]; float ur[8];
  // ---- prologue: chunk 0 loads ----
#pragma unroll
  for (int i = 0; i < 8; i++) ar[i] = *(const float4*)(Ab + (size_t)fq[i] * 256 + fk[i]);
#pragma unroll
  for (int i = 0; i < 8; i++) {
    const int l = ul[i], p = up[i];
    ur[i] = fmb[((l >> 4) * 8 + (p >> 3)) * 128 + (l & 15) * 8 + (p & 7)];
  }
  __syncthreads();  // nzc zeroed before atomics
#pragma unroll
  for (int i = 0; i < 8; i++) {
    At[fk[i] + 0][fq[i]] = ar[i].x; At[fk[i] + 1][fq[i]] = ar[i].y;
    At[fk[i] + 2][fq[i]] = ar[i].z; At[fk[i] + 3][fq[i]] = ar[i].w;
    *(float4*)(Ob + (size_t)fq[i] * 256 + fk[i]) = ar[i];
    int c4 = (ar[i].x != 0.f) + (ar[i].y != 0.f) + (ar[i].z != 0.f) + (ar[i].w != 0.f);
    c4 += __shfl_xor(c4, 1); c4 += __shfl_xor(c4, 2); c4 += __shfl_xor(c4, 4);
    if ((tid & 7) == 0) atomicAdd(&nzc[fq[i]], c4);
    Uts[ul[i]][up[i]] = ur[i];
  }
  __syncthreads();

  float acc[8][8];
#pragma unroll
  for (int j = 0; j < 8; j++)
#pragma unroll
    for (int i = 0; i < 8; i++) acc[j][i] = 0.f;

  for (int c = 0; c < 8; c++) {
    if (c < 7) {  // T14 issue-early: next chunk's global loads in flight
      const int kc = (c + 1) << 5;
#pragma unroll
      for (int i = 0; i < 8; i++) ar[i] = *(const float4*)(Ab + (size_t)fq[i] * 256 + kc + fk[i]);
#pragma unroll
      for (int i = 0; i < 8; i++) {
        const int l = kc + ul[i], p = up[i];
        ur[i] = fmb[((l >> 4) * 8 + (p >> 3)) * 128 + (l & 15) * 8 + (p & 7)];
      }
    }
    // ---- compute current chunk: 32 kk x 64 FMA ----
#pragma unroll 8
    for (int kk = 0; kk < 32; kk++) {
      float4 a0 = *(const float4*)&At[kk][q0];
      float4 a1 = *(const float4*)&At[kk][q0 + 4];
      float4 u0 = *(const float4*)&Uts[kk][p0];
      float4 u1 = *(const float4*)&Uts[kk][p0 + 4];
      const float av[8] = {a0.x, a0.y, a0.z, a0.w, a1.x, a1.y, a1.z, a1.w};
      const float uv[8] = {u0.x, u0.y, u0.z, u0.w, u1.x, u1.y, u1.z, u1.w};
#pragma unroll
      for (int j = 0; j < 8; j++)
#pragma unroll
        for (int i = 0; i < 8; i++) acc[j][i] += av[j] * uv[i];
    }
    __syncthreads();  // all waves done reading At/Uts
    if (c < 7) {      // write-late: stage next chunk, passthrough, nz count
      const int kc = (c + 1) << 5;
#pragma unroll
      for (int i = 0; i < 8; i++) {
        At[fk[i] + 0][fq[i]] = ar[i].x; At[fk[i] + 1][fq[i]] = ar[i].y;
        At[fk[i] + 2][fq[i]] = ar[i].z; At[fk[i] + 3][fq[i]] = ar[i].w;
        *(float4*)(Ob + (size_t)fq[i] * 256 + kc + fk[i]) = ar[i];
        int c4 = (ar[i].x != 0.f) + (ar[i].y != 0.f) + (ar[i].z != 0.f) + (ar[i].w != 0.f);
        c4 += __shfl_xor(c4, 1); c4 += __shfl_xor(c4, 2); c4 += __shfl_xor(c4, 4);
        if ((tid & 7) == 0) atomicAdd(&nzc[fq[i]], c4);
        Uts[ul[i]][up[i]] = ur[i];
      }
    }
    __syncthreads();
  }

  nzinv[(size_t)bc * 4096 + qb + tid] = 1.0f / ((float)nzc[tid] + 1e-5f);

#pragma unroll
  for (int j = 0; j < 8; j++) {
    float* cb = corr + (((size_t)bc * 4096 + qb + q0 + j) << 6) + p0;
    *(float4*)cb       = make_float4(acc[j][0], acc[j][1], acc[j][2], acc[j][3]);
    *(float4*)(cb + 4) = make_float4(acc[j][4], acc[j][5], acc[j][6], acc[j][7]);
  }
}

// ---------------------------------------------------------------------------
// K5: out = log_softmax_c( (corr[q,p]*nzinv + 1) * bilinear_up(y_small) )
// Block = 2 s-rows x 512 t. Separable bilinear: h-interp rows cached in LDS
// (G[2][8][65]); each thread handles 4 consecutive t (float4 corr/out).
// grid = 4 b * 256 s-pairs = 1024 blocks.
// ---------------------------------------------------------------------------
__global__ __launch_bounds__(256) void k_out(const float* __restrict__ corr,
                                             const float* __restrict__ nzinv,
                                             const float* __restrict__ ys,
                                             float* __restrict__ out) {
  __shared__ float G[2][8][65];
  const int bx = blockIdx.x;
  const int b = bx >> 8;
  const int s0 = (bx & 255) << 1;
  const int tid = threadIdx.x;
  const float* ysb = ys + ((size_t)b << 15);
#pragma unroll
  for (int j = 0; j < 4; j++) {
    const int e = tid + (j << 8);
    const int sl = e >> 9, c = (e >> 6) & 7, l = e & 63;
    const int s = s0 + sl;
    float ph = s * (63.0f / 511.0f); int lh = (int)ph; float wh = ph - (float)lh;
    const int dh = (lh < 63) ? 64 : 0;
    const float* yc = ysb + ((size_t)c << 12) + lh * 64 + l;
    G[sl][c][l] = (1.f - wh) * yc[0] + wh * yc[dh];
  }
  __syncthreads();

  const int sl = tid >> 7;
  const int s = s0 + sl;
  const int t0 = (tid & 127) << 2;
  const int q = ((s >> 3) << 6) + (t0 >> 3);
  const int p0 = ((s & 7) << 3) + (t0 & 7);

  float z[4][8];
#pragma unroll
  for (int c = 0; c < 8; c++) {
    const size_t bcp = (size_t)(b * 8 + c);
    const float4 cr = *(const float4*)&corr[(((bcp << 12) + q) << 6) + p0];
    const float rz = nzinv[(bcp << 12) + q];
    const float crv[4] = {cr.x, cr.y, cr.z, cr.w};
#pragma unroll
    for (int u = 0; u < 4; u++) {
      const float pw = (t0 + u) * (63.0f / 511.0f);
      const int lt = (int)pw; const float wtt = pw - (float)lt;
      const int hi = (lt < 63) ? lt + 1 : 63;
      const float yv = (1.f - wtt) * G[sl][c][lt] + wtt * G[sl][c][hi];
      z[u][c] = (crv[u] * rz + 1.0f) * yv;
    }
  }
  const size_t ob = ((size_t)b << 21) + ((size_t)s << 9) + t0;
#pragma unroll
  for (int c = 0; c < 8; c++) {
    float4 o;
#pragma unroll
    for (int u = 0; u < 4; u++) {
      float m = z[u][0];
#pragma unroll
      for (int cc = 1; cc < 8; cc++) m = fmaxf(m, z[u][cc]);
      float sum = 0.f;
#pragma unroll
      for (int cc = 0; cc < 8; cc++) sum += __expf(z[u][cc] - m);
      const float v = z[u][c] - m - __logf(sum);
      if (u == 0) o.x = v; else if (u == 1) o.y = v; else if (u == 2) o.z = v; else o.w = v;
    }
    *(float4*)&out[ob + ((size_t)c << 18)] = o;
  }
}

// ---------------------------------------------------------------------------
extern "C" void kernel_launch(void* const* d_in, const int* in_sizes, int n_in,
                              void* d_out, int out_size, void* d_ws, size_t ws_size,
                              hipStream_t stream) {
  const float* x   = (const float*)d_in[0];   // [4,256,64,64]
  const float* att = (const float*)d_in[1];   // [4,8,4096,256]
  const float* cw  = (const float*)d_in[2];   // [8,256]
  const float* cb  = (const float*)d_in[3];   // [8]
  float* out1 = (float*)d_out;                          // [4,8,512,512]
  float* out2 = out1 + (size_t)4 * 8 * 512 * 512;       // attentions passthrough
  float* ws = (float*)d_ws;
  float* y_small = ws;                 // 131072  [4,8,64,64]
  float* fm      = ws + 131072;        // 524288  [4,8,128,128]
  float* nzinv   = ws + 655360;        // 131072  [4,8,4096]
  float* corr    = ws + 786432;        // 8388608 [4,8,4096,64]

  k_conv<<<256, 256, 0, stream>>>(x, cw, cb, y_small);
  k_pool<<<256, 256, 0, stream>>>(y_small, fm);
  dim3 g4(16, 32);
  k_corr<<<g4, 256, 0, stream>>>(att, fm, out2, corr, nzinv);
  k_out<<<1024, 256, 0, stream>>>(corr, nzinv, y_small, out1);
}